// Round 2
// baseline (9294.897 us; speedup 1.0000x reference)
//
#include <hip/hip_runtime.h>
#include <hip/hip_cooperative_groups.h>
#include <cstdint>
#include <cstddef>

namespace cg = cooperative_groups;

typedef __attribute__((ext_vector_type(8))) short s16x8;
typedef __attribute__((ext_vector_type(4))) short s16x4;
typedef __attribute__((ext_vector_type(4))) float f32x4;

#define HID 1024
#define BATCH 32
#define SEQ 512

__device__ __forceinline__ short f2bf(float f){
  unsigned u = __builtin_bit_cast(unsigned, f);
  u = (u + 0x7fffu + ((u >> 16) & 1u)) >> 16;
  return (short)u;
}
__device__ __forceinline__ float bf2f(short s){
  unsigned u = ((unsigned)(unsigned short)s) << 16;
  return __builtin_bit_cast(float, u);
}

// ---------------- pack x into A-fragment tiles ----------------
// xpk layout: [mb(128)][kt(16)] tiles of 1024 units; unit = (ks*8+mt)*64+lane,
// holds x[mb*128+mt*16+(lane&15)][kt*64+ks*32+(lane>>4)*8 + j], j=0..7
__global__ __launch_bounds__(256) void pack_x_kernel(const float* __restrict__ x,
                                                     s16x8* __restrict__ xpk){
  int P = blockIdx.x * 256 + threadIdx.x;      // 2,097,152 total
  int lane = P & 63;
  int w = (P >> 6) & 15; int ks = w >> 3, mt = w & 7;
  int tile = P >> 10; int kt = tile & 15; int mb = tile >> 4;
  int row = mb * 128 + mt * 16 + (lane & 15);
  int k0 = kt * 64 + ks * 32 + (lane >> 4) * 8;
  const f32x4* src = (const f32x4*)(x + (size_t)row * HID + k0);
  f32x4 v0 = src[0], v1 = src[1];
  s16x8 o;
  o[0]=f2bf(v0[0]); o[1]=f2bf(v0[1]); o[2]=f2bf(v0[2]); o[3]=f2bf(v0[3]);
  o[4]=f2bf(v1[0]); o[5]=f2bf(v1[1]); o[6]=f2bf(v1[2]); o[7]=f2bf(v1[3]);
  xpk[P] = o;
}

// ---------------- pack input weights (4 gates side by side, N=4096) ----------------
__global__ __launch_bounds__(256) void pack_wx_kernel(const float* __restrict__ Wii,
    const float* __restrict__ Wif, const float* __restrict__ Wig,
    const float* __restrict__ Wio, s16x8* __restrict__ wxpk){
  int P = blockIdx.x * 256 + threadIdx.x;      // 524,288 total
  int lane = P & 63;
  int w = (P >> 6) & 15; int ks = w >> 3, nt = w & 7;
  int tile = P >> 10; int kt = tile & 15; int nb = tile >> 4;
  int n = nb * 128 + nt * 16 + (lane & 15);
  int g = n >> 10, c = n & 1023;
  int k0 = kt * 64 + ks * 32 + (lane >> 4) * 8;
  const float* W = (g == 0) ? Wii : (g == 1) ? Wif : (g == 2) ? Wig : Wio;
  s16x8 o;
  #pragma unroll
  for (int j = 0; j < 8; ++j) o[j] = f2bf(W[(size_t)(k0 + j) * HID + c]);
  wxpk[P] = o;
}

// ---------------- pack recurrent weights per rec-kernel workgroup ----------------
// whpk: [wg(128)][kt(16)][ks(2)][nt(2)][lane][8]; col16=lane&15,
// gate = nt*2 + (col16>>3), c = wg*8 + (col16&7), k = kt*64+ks*32+(lane>>4)*8+j
__global__ __launch_bounds__(256) void pack_wh_kernel(const float* __restrict__ Whi,
    const float* __restrict__ Whf, const float* __restrict__ Whg,
    const float* __restrict__ Who, s16x8* __restrict__ whpk){
  int P = blockIdx.x * 256 + threadIdx.x;      // 524,288 total
  int lane = P & 63;
  int q = P >> 6;
  int nt = q & 1; int ks = (q >> 1) & 1; int kt = (q >> 2) & 15; int wg = q >> 6;
  int col16 = lane & 15;
  int g = nt * 2 + (col16 >> 3);
  int c = wg * 8 + (col16 & 7);
  int k0 = kt * 64 + ks * 32 + (lane >> 4) * 8;
  const float* W = (g == 0) ? Whi : (g == 1) ? Whf : (g == 2) ? Whg : Who;
  s16x8 o;
  #pragma unroll
  for (int j = 0; j < 8; ++j) o[j] = f2bf(W[(size_t)(k0 + j) * HID + c]);
  whpk[P] = o;
}

// ---------------- init: bias sums, h0 packed ----------------
__global__ __launch_bounds__(256) void init_kernel(const float* __restrict__ h0,
    const float* bii, const float* bif, const float* big, const float* bio,
    const float* bhi, const float* bhf, const float* bhg, const float* bho,
    float* __restrict__ bias_sum, s16x8* __restrict__ hA0){
  int T = blockIdx.x * 256 + threadIdx.x;
  if (T < 4096){
    int g = T >> 10, c = T & 1023;
    const float* bi = (g == 0) ? bii : (g == 1) ? bif : (g == 2) ? big : bio;
    const float* bh = (g == 0) ? bhi : (g == 1) ? bhf : (g == 2) ? bhg : bho;
    bias_sum[T] = bi[c] + bh[c];
  } else if (T < 8192){
    int u = T - 4096;                 // 4096 units of 8 bf16
    int lane = u & 63; int q = u >> 6;
    int kstep = q & 31; int mtb = q >> 5;
    int b = mtb * 16 + (lane & 15);
    int col0 = kstep * 32 + (lane >> 4) * 8;
    const float* src = h0 + (size_t)b * HID + col0;
    s16x8 o;
    #pragma unroll
    for (int j = 0; j < 8; ++j) o[j] = f2bf(src[j]);
    hA0[u] = o;
  }
}

// ---------------- phase 1: XP = x @ [Wii|Wif|Wig|Wio] + (b_i + b_h) ----------------
// 128x128 tile, BK=64, 4 waves, 4x4 frags. Output: XP[t][b][c][gate] bf16 (8B/thread read later).
__global__ __launch_bounds__(256) void gemm_xp_kernel(const s16x8* __restrict__ xpk,
    const s16x8* __restrict__ wxpk, const float* __restrict__ bias_sum,
    short* __restrict__ XP){
  const int mb = blockIdx.x, nb = blockIdx.y;
  const int tid = threadIdx.x, lane = tid & 63, wave = tid >> 6;
  const int wr = wave >> 1, wc = wave & 1;
  __shared__ s16x8 sA[1024];   // 16KB
  __shared__ s16x8 sB[1024];   // 16KB
  f32x4 acc[4][4] = {};
  const s16x8* gA = xpk + (size_t)(mb * 16) * 1024;
  const s16x8* gB = wxpk + (size_t)(nb * 16) * 1024;
  for (int kt = 0; kt < 16; ++kt){
    __syncthreads();
    #pragma unroll
    for (int i = 0; i < 4; ++i){
      sA[i * 256 + tid] = gA[(size_t)kt * 1024 + i * 256 + tid];
      sB[i * 256 + tid] = gB[(size_t)kt * 1024 + i * 256 + tid];
    }
    __syncthreads();
    #pragma unroll
    for (int ks = 0; ks < 2; ++ks){
      s16x8 af[4], bfr[4];
      #pragma unroll
      for (int i = 0; i < 4; ++i) af[i] = sA[(ks * 8 + wr * 4 + i) * 64 + lane];
      #pragma unroll
      for (int j = 0; j < 4; ++j) bfr[j] = sB[(ks * 8 + wc * 4 + j) * 64 + lane];
      #pragma unroll
      for (int i = 0; i < 4; ++i)
        #pragma unroll
        for (int j = 0; j < 4; ++j)
          acc[i][j] = __builtin_amdgcn_mfma_f32_16x16x32_bf16(af[i], bfr[j], acc[i][j], 0, 0, 0);
    }
  }
  #pragma unroll
  for (int i = 0; i < 4; ++i){
    const int m_base = mb * 128 + (wr * 4 + i) * 16 + ((lane >> 4) << 2);
    #pragma unroll
    for (int j = 0; j < 4; ++j){
      const int n = nb * 128 + (wc * 4 + j) * 16 + (lane & 15);
      const float bias = bias_sum[n];
      const int g = n >> 10, c = n & 1023;
      #pragma unroll
      for (int r = 0; r < 4; ++r){
        const int m = m_base + r;
        const int tt = m & 511, bb = m >> 9;
        // XP[t][b][c][g]
        XP[(((size_t)(tt * 32 + bb) << 10) + c) * 4 + g] = f2bf(acc[i][j][r] + bias);
      }
    }
  }
}

// ---------------- phase 2: persistent recurrence, all 512 steps ----------------
// 128 WGs x 256 thr. WG wg owns h-cols [wg*8, wg*8+8) x 4 gates. W_h slice in LDS (64KB).
// c-state in register. h ping-pongs in packed-fragment global buffers; grid.sync per step.
__global__ __launch_bounds__(256, 1) void lstm_rec_kernel(const s16x8* __restrict__ whpk,
    s16x8* __restrict__ hA, s16x8* __restrict__ hB, const short* __restrict__ XP,
    const float* __restrict__ c0, float* __restrict__ out, float* __restrict__ htct)
{
  extern __shared__ char smem[];
  s16x8* sW  = (s16x8*)smem;               // 64KB: [kt*2ks*2nt interleave][lane]
  float* pre = (float*)(smem + 65536);     // [32][33] padded
  cg::grid_group grid = cg::this_grid();

  const int wg = blockIdx.x;
  const int tid = threadIdx.x, lane = tid & 63, wave = tid >> 6;
  const int mt = wave >> 1, nt = wave & 1;

  // stage this WG's W_h slice into LDS once
  {
    const s16x8* gW = whpk + (size_t)wg * 4096;
    #pragma unroll
    for (int i = 0; i < 16; ++i) sW[i * 256 + tid] = gW[i * 256 + tid];
  }

  // per-thread epilogue identity
  const int b = tid >> 3, cc = tid & 7;
  const int hcol = wg * 8 + cc;
  float c = c0[b * HID + hcol];
  // packed-h store offset (constant over t)
  const int kstep = hcol >> 5, hi = (hcol >> 3) & 3, jj = hcol & 7;
  const size_t hoff = (((size_t)((b >> 4) * 32 + kstep) * 64 + hi * 16 + (b & 15)) << 3) + jj;

  const int prow = mt * 16 + ((lane >> 4) << 2);
  const int pcol = nt * 16 + (lane & 15);

  const s16x8* h_cur = hA;
  s16x8* h_nxt = hB;

  __syncthreads();

  for (int t = 0; t < SEQ; ++t){
    f32x4 acc = {0.f, 0.f, 0.f, 0.f};
    #pragma unroll
    for (int kk = 0; kk < 32; ++kk){
      s16x8 a = h_cur[(mt * 32 + kk) * 64 + lane];
      s16x8 w = sW[(kk * 2 + nt) * 64 + lane];
      acc = __builtin_amdgcn_mfma_f32_16x16x32_bf16(a, w, acc, 0, 0, 0);
    }
    pre[(prow + 0) * 33 + pcol] = acc[0];
    pre[(prow + 1) * 33 + pcol] = acc[1];
    pre[(prow + 2) * 33 + pcol] = acc[2];
    pre[(prow + 3) * 33 + pcol] = acc[3];
    __syncthreads();

    s16x4 xp = *(const s16x4*)(XP + ((((size_t)t * 32 + b) << 10) + hcol) * 4);
    float p0 = pre[b * 33 + 0 * 8 + cc] + bf2f(xp[0]);
    float p1 = pre[b * 33 + 1 * 8 + cc] + bf2f(xp[1]);
    float p2 = pre[b * 33 + 2 * 8 + cc] + bf2f(xp[2]);
    float p3 = pre[b * 33 + 3 * 8 + cc] + bf2f(xp[3]);
    float ig = 1.f / (1.f + __expf(-p0));
    float fg = 1.f / (1.f + __expf(-p1));
    float gg = tanhf(p2);
    float og = 1.f / (1.f + __expf(-p3));
    c = fg * c + ig * gg;
    float h = og * tanhf(c);
    out[((size_t)b * SEQ + t) * HID + hcol] = h;
    ((short*)h_nxt)[hoff] = f2bf(h);
    if (t == SEQ - 1){
      htct[b * HID + hcol] = h;
      htct[32 * HID + b * HID + hcol] = c;
    }
    // swap ping-pong
    s16x8* tmp = (s16x8*)h_cur; h_cur = h_nxt; h_nxt = tmp;
    grid.sync();
  }
}

extern "C" void kernel_launch(void* const* d_in, const int* in_sizes, int n_in,
                              void* d_out, int out_size, void* d_ws, size_t ws_size,
                              hipStream_t stream){
  const float* x   = (const float*)d_in[0];
  const float* h0  = (const float*)d_in[1];
  const float* c0  = (const float*)d_in[2];
  const float* Wii = (const float*)d_in[3];
  const float* Wif = (const float*)d_in[4];
  const float* Wig = (const float*)d_in[5];
  const float* Wio = (const float*)d_in[6];
  const float* Whi = (const float*)d_in[7];
  const float* Whf = (const float*)d_in[8];
  const float* Whg = (const float*)d_in[9];
  const float* Who = (const float*)d_in[10];
  const float* bii = (const float*)d_in[11];
  const float* bif = (const float*)d_in[12];
  const float* big = (const float*)d_in[13];
  const float* bio = (const float*)d_in[14];
  const float* bhi = (const float*)d_in[15];
  const float* bhf = (const float*)d_in[16];
  const float* bhg = (const float*)d_in[17];
  const float* bho = (const float*)d_in[18];

  char* ws = (char*)d_ws;
  s16x8* xpk      = (s16x8*)(ws);                         // 32 MB
  s16x8* wxpk     = (s16x8*)(ws + 33554432ull);           //  8 MB
  s16x8* whpk     = (s16x8*)(ws + 41943040ull);           //  8 MB
  short* XP       = (short*)(ws + 50331648ull);           // 128 MB
  s16x8* hA0      = (s16x8*)(ws + 184549376ull);          // 64 KB
  s16x8* hA1      = (s16x8*)(ws + 184614912ull);          // 64 KB
  float* bias_sum = (float*)(ws + 184811520ull);          // 16 KB

  float* out  = (float*)d_out;
  float* htct = out + (size_t)BATCH * SEQ * HID;

  pack_x_kernel<<<8192, 256, 0, stream>>>(x, xpk);
  pack_wx_kernel<<<2048, 256, 0, stream>>>(Wii, Wif, Wig, Wio, wxpk);
  pack_wh_kernel<<<2048, 256, 0, stream>>>(Whi, Whf, Whg, Who, whpk);
  init_kernel<<<32, 256, 0, stream>>>(h0, bii, bif, big, bio,
                                      bhi, bhf, bhg, bho, bias_sum, hA0);
  gemm_xp_kernel<<<dim3(128, 32), 256, 0, stream>>>(xpk, wxpk, bias_sum, XP);

  void* args[] = {(void*)&whpk, (void*)&hA0, (void*)&hA1, (void*)&XP,
                  (void*)&c0, (void*)&out, (void*)&htct};
  hipLaunchCooperativeKernel((const void*)lstm_rec_kernel, dim3(128), dim3(256),
                             args, 65536 + 32 * 33 * 4, stream);
}

// Round 3
// 6423.441 us; speedup vs baseline: 1.4470x; 1.4470x over previous
//
#include <hip/hip_runtime.h>
#include <cstdint>
#include <cstddef>

typedef __attribute__((ext_vector_type(8))) short s16x8;
typedef __attribute__((ext_vector_type(4))) short s16x4;
typedef __attribute__((ext_vector_type(4))) float f32x4;

#define HID 1024
#define BATCH 32
#define SEQ 512
#define NWG 128

__device__ __forceinline__ short f2bf(float f){
  unsigned u = __builtin_bit_cast(unsigned, f);
  u = (u + 0x7fffu + ((u >> 16) & 1u)) >> 16;
  return (short)u;
}
__device__ __forceinline__ float bf2f(short s){
  unsigned u = ((unsigned)(unsigned short)s) << 16;
  return __builtin_bit_cast(float, u);
}

// ---------------- pack x into A-fragment tiles ----------------
__global__ __launch_bounds__(256) void pack_x_kernel(const float* __restrict__ x,
                                                     s16x8* __restrict__ xpk){
  int P = blockIdx.x * 256 + threadIdx.x;      // 2,097,152 total
  int lane = P & 63;
  int w = (P >> 6) & 15; int ks = w >> 3, mt = w & 7;
  int tile = P >> 10; int kt = tile & 15; int mb = tile >> 4;
  int row = mb * 128 + mt * 16 + (lane & 15);
  int k0 = kt * 64 + ks * 32 + (lane >> 4) * 8;
  const f32x4* src = (const f32x4*)(x + (size_t)row * HID + k0);
  f32x4 v0 = src[0], v1 = src[1];
  s16x8 o;
  o[0]=f2bf(v0[0]); o[1]=f2bf(v0[1]); o[2]=f2bf(v0[2]); o[3]=f2bf(v0[3]);
  o[4]=f2bf(v1[0]); o[5]=f2bf(v1[1]); o[6]=f2bf(v1[2]); o[7]=f2bf(v1[3]);
  xpk[P] = o;
}

// ---------------- pack input weights (4 gates side by side, N=4096) ----------------
__global__ __launch_bounds__(256) void pack_wx_kernel(const float* __restrict__ Wii,
    const float* __restrict__ Wif, const float* __restrict__ Wig,
    const float* __restrict__ Wio, s16x8* __restrict__ wxpk){
  int P = blockIdx.x * 256 + threadIdx.x;      // 524,288 total
  int lane = P & 63;
  int w = (P >> 6) & 15; int ks = w >> 3, nt = w & 7;
  int tile = P >> 10; int kt = tile & 15; int nb = tile >> 4;
  int n = nb * 128 + nt * 16 + (lane & 15);
  int g = n >> 10, c = n & 1023;
  int k0 = kt * 64 + ks * 32 + (lane >> 4) * 8;
  const float* W = (g == 0) ? Wii : (g == 1) ? Wif : (g == 2) ? Wig : Wio;
  s16x8 o;
  #pragma unroll
  for (int j = 0; j < 8; ++j) o[j] = f2bf(W[(size_t)(k0 + j) * HID + c]);
  wxpk[P] = o;
}

// ---------------- pack recurrent weights per rec-kernel workgroup ----------------
// whpk: [wg(128)][kt(16)][ks(2)][nt(2)][lane][8]; col16=lane&15,
// gate = nt*2 + (col16>>3), c = wg*8 + (col16&7), k = kt*64+ks*32+(lane>>4)*8+j
__global__ __launch_bounds__(256) void pack_wh_kernel(const float* __restrict__ Whi,
    const float* __restrict__ Whf, const float* __restrict__ Whg,
    const float* __restrict__ Who, s16x8* __restrict__ whpk){
  int P = blockIdx.x * 256 + threadIdx.x;      // 524,288 total
  int lane = P & 63;
  int q = P >> 6;
  int nt = q & 1; int ks = (q >> 1) & 1; int kt = (q >> 2) & 15; int wg = q >> 6;
  int col16 = lane & 15;
  int g = nt * 2 + (col16 >> 3);
  int c = wg * 8 + (col16 & 7);
  int k0 = kt * 64 + ks * 32 + (lane >> 4) * 8;
  const float* W = (g == 0) ? Whi : (g == 1) ? Whf : (g == 2) ? Whg : Who;
  s16x8 o;
  #pragma unroll
  for (int j = 0; j < 8; ++j) o[j] = f2bf(W[(size_t)(k0 + j) * HID + c]);
  whpk[P] = o;
}

// ---------------- init: bias sums, h0 packed, barrier reset ----------------
__global__ __launch_bounds__(256) void init_kernel(const float* __restrict__ h0,
    const float* bii, const float* bif, const float* big, const float* bio,
    const float* bhi, const float* bhf, const float* bhg, const float* bho,
    float* __restrict__ bias_sum, s16x8* __restrict__ hA0, int* __restrict__ bar){
  int T = blockIdx.x * 256 + threadIdx.x;
  if (T < 4096){
    int g = T >> 10, c = T & 1023;
    const float* bi = (g == 0) ? bii : (g == 1) ? bif : (g == 2) ? big : bio;
    const float* bh = (g == 0) ? bhi : (g == 1) ? bhf : (g == 2) ? bhg : bho;
    bias_sum[T] = bi[c] + bh[c];
  } else if (T < 8192){
    int u = T - 4096;                 // 4096 units of 8 bf16
    int lane = u & 63; int q = u >> 6;
    int kstep = q & 31; int mtb = q >> 5;
    int b = mtb * 16 + (lane & 15);
    int col0 = kstep * 32 + (lane >> 4) * 8;
    const float* src = h0 + (size_t)b * HID + col0;
    s16x8 o;
    #pragma unroll
    for (int j = 0; j < 8; ++j) o[j] = f2bf(src[j]);
    hA0[u] = o;
  } else if (T < 8192 + 17){
    bar[T - 8192] = 0;                // 16 leaf counters + 1 root
  }
}

// ---------------- phase 1: XP = x @ [Wii|Wif|Wig|Wio] + (b_i + b_h) ----------------
// Output: XP[t][b][c][gate] bf16 (8B/thread read in recurrence).
__global__ __launch_bounds__(256) void gemm_xp_kernel(const s16x8* __restrict__ xpk,
    const s16x8* __restrict__ wxpk, const float* __restrict__ bias_sum,
    short* __restrict__ XP){
  const int mb = blockIdx.x, nb = blockIdx.y;
  const int tid = threadIdx.x, lane = tid & 63, wave = tid >> 6;
  const int wr = wave >> 1, wc = wave & 1;
  __shared__ s16x8 sA[1024];   // 16KB
  __shared__ s16x8 sB[1024];   // 16KB
  f32x4 acc[4][4] = {};
  const s16x8* gA = xpk + (size_t)(mb * 16) * 1024;
  const s16x8* gB = wxpk + (size_t)(nb * 16) * 1024;
  for (int kt = 0; kt < 16; ++kt){
    __syncthreads();
    #pragma unroll
    for (int i = 0; i < 4; ++i){
      sA[i * 256 + tid] = gA[(size_t)kt * 1024 + i * 256 + tid];
      sB[i * 256 + tid] = gB[(size_t)kt * 1024 + i * 256 + tid];
    }
    __syncthreads();
    #pragma unroll
    for (int ks = 0; ks < 2; ++ks){
      s16x8 af[4], bfr[4];
      #pragma unroll
      for (int i = 0; i < 4; ++i) af[i] = sA[(ks * 8 + wr * 4 + i) * 64 + lane];
      #pragma unroll
      for (int j = 0; j < 4; ++j) bfr[j] = sB[(ks * 8 + wc * 4 + j) * 64 + lane];
      #pragma unroll
      for (int i = 0; i < 4; ++i)
        #pragma unroll
        for (int j = 0; j < 4; ++j)
          acc[i][j] = __builtin_amdgcn_mfma_f32_16x16x32_bf16(af[i], bfr[j], acc[i][j], 0, 0, 0);
    }
  }
  #pragma unroll
  for (int i = 0; i < 4; ++i){
    const int m_base = mb * 128 + (wr * 4 + i) * 16 + ((lane >> 4) << 2);
    #pragma unroll
    for (int j = 0; j < 4; ++j){
      const int n = nb * 128 + (wc * 4 + j) * 16 + (lane & 15);
      const float bias = bias_sum[n];
      const int g = n >> 10, c = n & 1023;
      #pragma unroll
      for (int r = 0; r < 4; ++r){
        const int m = m_base + r;
        const int tt = m & 511, bb = m >> 9;
        XP[(((size_t)(tt * 32 + bb) << 10) + c) * 4 + g] = f2bf(acc[i][j][r] + bias);
      }
    }
  }
}

// ---------------- phase 2: persistent recurrence with hand-rolled grid barrier ----------------
// 128 WGs x 256 thr. WG wg owns h-cols [wg*8, wg*8+8) x 4 gates. W_h slice in LDS (64KB).
// Two-level monotonic barrier: 16 leaf counters (8 WGs each) -> 1 root; agent-scope fences.
__global__ __launch_bounds__(256, 1) void lstm_rec_kernel(const s16x8* __restrict__ whpk,
    s16x8* __restrict__ hA, s16x8* __restrict__ hB, const short* __restrict__ XP,
    const float* __restrict__ c0, float* __restrict__ out, float* __restrict__ htct,
    int* __restrict__ bar)
{
  extern __shared__ char smem[];
  s16x8* sW  = (s16x8*)smem;               // 64KB
  float* pre = (float*)(smem + 65536);     // [32][33] padded

  const int wg = blockIdx.x;
  const int tid = threadIdx.x, lane = tid & 63, wave = tid >> 6;
  const int mt = wave >> 1, nt = wave & 1;

  // stage this WG's W_h slice into LDS once
  {
    const s16x8* gW = whpk + (size_t)wg * 4096;
    #pragma unroll
    for (int i = 0; i < 16; ++i) sW[i * 256 + tid] = gW[i * 256 + tid];
  }

  // per-thread epilogue identity
  const int b = tid >> 3, cc = tid & 7;
  const int hcol = wg * 8 + cc;
  float c = c0[b * HID + hcol];
  const int kstep = hcol >> 5, hi = (hcol >> 3) & 3, jj = hcol & 7;
  const size_t hoff = (((size_t)((b >> 4) * 32 + kstep) * 64 + hi * 16 + (b & 15)) << 3) + jj;

  const int prow = mt * 16 + ((lane >> 4) << 2);
  const int pcol = nt * 16 + (lane & 15);

  const s16x8* h_cur = hA;
  s16x8* h_nxt = hB;

  // prefetch XP for t=0
  s16x4 xp = *(const s16x4*)(XP + ((((size_t)b) << 10) + hcol) * 4);

  __syncthreads();

  for (int t = 0; t < SEQ; ++t){
    f32x4 acc = {0.f, 0.f, 0.f, 0.f};
    #pragma unroll
    for (int kk = 0; kk < 32; ++kk){
      s16x8 a = h_cur[(mt * 32 + kk) * 64 + lane];
      s16x8 w = sW[(kk * 2 + nt) * 64 + lane];
      acc = __builtin_amdgcn_mfma_f32_16x16x32_bf16(a, w, acc, 0, 0, 0);
    }
    pre[(prow + 0) * 33 + pcol] = acc[0];
    pre[(prow + 1) * 33 + pcol] = acc[1];
    pre[(prow + 2) * 33 + pcol] = acc[2];
    pre[(prow + 3) * 33 + pcol] = acc[3];
    __syncthreads();

    float p0 = pre[b * 33 + 0 * 8 + cc] + bf2f(xp[0]);
    float p1 = pre[b * 33 + 1 * 8 + cc] + bf2f(xp[1]);
    float p2 = pre[b * 33 + 2 * 8 + cc] + bf2f(xp[2]);
    float p3 = pre[b * 33 + 3 * 8 + cc] + bf2f(xp[3]);
    float ig = 1.f / (1.f + __expf(-p0));
    float fg = 1.f / (1.f + __expf(-p1));
    float gg = tanhf(p2);
    float og = 1.f / (1.f + __expf(-p3));
    c = fg * c + ig * gg;
    float h = og * tanhf(c);
    out[((size_t)b * SEQ + t) * HID + hcol] = h;
    ((short*)h_nxt)[hoff] = f2bf(h);
    if (t == SEQ - 1){
      htct[b * HID + hcol] = h;
      htct[32 * HID + b * HID + hcol] = c;
      break;                      // no barrier needed after final step
    }

    // prefetch XP for t+1 (latency hides under the barrier)
    const int tn = t + 1;
    s16x4 xp_n = *(const s16x4*)(XP + ((((size_t)tn * 32 + b) << 10) + hcol) * 4);

    // ---- grid barrier (two-level, monotonic epochs) ----
    __syncthreads();              // all stores of this WG drained to L2
    if (tid == 0){
      __builtin_amdgcn_fence(__ATOMIC_RELEASE, "agent");
      int old = __hip_atomic_fetch_add(&bar[wg & 15], 1, __ATOMIC_RELAXED,
                                       __HIP_MEMORY_SCOPE_AGENT);
      if (old == 8 * (t + 1) - 1)
        __hip_atomic_fetch_add(&bar[16], 1, __ATOMIC_RELAXED,
                               __HIP_MEMORY_SCOPE_AGENT);
      while (__hip_atomic_load(&bar[16], __ATOMIC_RELAXED,
                               __HIP_MEMORY_SCOPE_AGENT) < 16 * (t + 1))
        __builtin_amdgcn_s_sleep(2);
    }
    __syncthreads();
    __builtin_amdgcn_fence(__ATOMIC_ACQUIRE, "agent");
    // ----------------------------------------------------

    xp = xp_n;
    s16x8* tmp = (s16x8*)h_cur; h_cur = h_nxt; h_nxt = tmp;
  }
}

extern "C" void kernel_launch(void* const* d_in, const int* in_sizes, int n_in,
                              void* d_out, int out_size, void* d_ws, size_t ws_size,
                              hipStream_t stream){
  const float* x   = (const float*)d_in[0];
  const float* h0  = (const float*)d_in[1];
  const float* c0  = (const float*)d_in[2];
  const float* Wii = (const float*)d_in[3];
  const float* Wif = (const float*)d_in[4];
  const float* Wig = (const float*)d_in[5];
  const float* Wio = (const float*)d_in[6];
  const float* Whi = (const float*)d_in[7];
  const float* Whf = (const float*)d_in[8];
  const float* Whg = (const float*)d_in[9];
  const float* Who = (const float*)d_in[10];
  const float* bii = (const float*)d_in[11];
  const float* bif = (const float*)d_in[12];
  const float* big = (const float*)d_in[13];
  const float* bio = (const float*)d_in[14];
  const float* bhi = (const float*)d_in[15];
  const float* bhf = (const float*)d_in[16];
  const float* bhg = (const float*)d_in[17];
  const float* bho = (const float*)d_in[18];

  char* ws = (char*)d_ws;
  s16x8* xpk      = (s16x8*)(ws);                         // 32 MB
  s16x8* wxpk     = (s16x8*)(ws + 33554432ull);           //  8 MB
  s16x8* whpk     = (s16x8*)(ws + 41943040ull);           //  8 MB
  short* XP       = (short*)(ws + 50331648ull);           // 128 MB
  s16x8* hA0      = (s16x8*)(ws + 184549376ull);          // 64 KB
  s16x8* hA1      = (s16x8*)(ws + 184614912ull);          // 64 KB
  float* bias_sum = (float*)(ws + 184811520ull);          // 16 KB
  int*   bar      = (int*)  (ws + 184827904ull);          // 17 ints

  float* out  = (float*)d_out;
  float* htct = out + (size_t)BATCH * SEQ * HID;

  pack_x_kernel<<<8192, 256, 0, stream>>>(x, xpk);
  pack_wx_kernel<<<2048, 256, 0, stream>>>(Wii, Wif, Wig, Wio, wxpk);
  pack_wh_kernel<<<2048, 256, 0, stream>>>(Whi, Whf, Whg, Who, whpk);
  init_kernel<<<33, 256, 0, stream>>>(h0, bii, bif, big, bio,
                                      bhi, bhf, bhg, bho, bias_sum, hA0, bar);
  gemm_xp_kernel<<<dim3(128, 32), 256, 0, stream>>>(xpk, wxpk, bias_sum, XP);

  void* args[] = {(void*)&whpk, (void*)&hA0, (void*)&hA1, (void*)&XP,
                  (void*)&c0, (void*)&out, (void*)&htct, (void*)&bar};
  hipLaunchCooperativeKernel((const void*)lstm_rec_kernel, dim3(NWG), dim3(256),
                             args, 65536 + 32 * 33 * 4, stream);
}

// Round 4
// 4027.057 us; speedup vs baseline: 2.3081x; 1.5951x over previous
//
#include <hip/hip_runtime.h>
#include <cstdint>
#include <cstddef>

typedef __attribute__((ext_vector_type(8))) short s16x8;
typedef __attribute__((ext_vector_type(4))) short s16x4;
typedef __attribute__((ext_vector_type(4))) float f32x4;
typedef unsigned long long u64;

#define HID 1024
#define BATCH 32
#define SEQ 512
#define NWG 128

__device__ __forceinline__ short f2bf(float f){
  unsigned u = __builtin_bit_cast(unsigned, f);
  u = (u + 0x7fffu + ((u >> 16) & 1u)) >> 16;
  return (short)u;
}
__device__ __forceinline__ float bf2f(short s){
  unsigned u = ((unsigned)(unsigned short)s) << 16;
  return __builtin_bit_cast(float, u);
}

union U128 { struct { u64 lo, hi; } q; s16x8 v; };

// ---------------- pack x into A-fragment tiles ----------------
__global__ __launch_bounds__(256) void pack_x_kernel(const float* __restrict__ x,
                                                     s16x8* __restrict__ xpk){
  int P = blockIdx.x * 256 + threadIdx.x;      // 2,097,152 total
  int lane = P & 63;
  int w = (P >> 6) & 15; int ks = w >> 3, mt = w & 7;
  int tile = P >> 10; int kt = tile & 15; int mb = tile >> 4;
  int row = mb * 128 + mt * 16 + (lane & 15);
  int k0 = kt * 64 + ks * 32 + (lane >> 4) * 8;
  const f32x4* src = (const f32x4*)(x + (size_t)row * HID + k0);
  f32x4 v0 = src[0], v1 = src[1];
  s16x8 o;
  o[0]=f2bf(v0[0]); o[1]=f2bf(v0[1]); o[2]=f2bf(v0[2]); o[3]=f2bf(v0[3]);
  o[4]=f2bf(v1[0]); o[5]=f2bf(v1[1]); o[6]=f2bf(v1[2]); o[7]=f2bf(v1[3]);
  xpk[P] = o;
}

// ---------------- pack input weights (4 gates side by side, N=4096) ----------------
__global__ __launch_bounds__(256) void pack_wx_kernel(const float* __restrict__ Wii,
    const float* __restrict__ Wif, const float* __restrict__ Wig,
    const float* __restrict__ Wio, s16x8* __restrict__ wxpk){
  int P = blockIdx.x * 256 + threadIdx.x;      // 524,288 total
  int lane = P & 63;
  int w = (P >> 6) & 15; int ks = w >> 3, nt = w & 7;
  int tile = P >> 10; int kt = tile & 15; int nb = tile >> 4;
  int n = nb * 128 + nt * 16 + (lane & 15);
  int g = n >> 10, c = n & 1023;
  int k0 = kt * 64 + ks * 32 + (lane >> 4) * 8;
  const float* W = (g == 0) ? Wii : (g == 1) ? Wif : (g == 2) ? Wig : Wio;
  s16x8 o;
  #pragma unroll
  for (int j = 0; j < 8; ++j) o[j] = f2bf(W[(size_t)(k0 + j) * HID + c]);
  wxpk[P] = o;
}

// ---------------- pack recurrent weights per rec-kernel workgroup ----------------
// whpk: [wg(128)][kt(16)][ks(2)][nt(2)][lane][8]; col16=lane&15,
// gate = nt*2 + (col16>>3), c = wg*8 + (col16&7), k = kt*64+ks*32+(lane>>4)*8+j
__global__ __launch_bounds__(256) void pack_wh_kernel(const float* __restrict__ Whi,
    const float* __restrict__ Whf, const float* __restrict__ Whg,
    const float* __restrict__ Who, s16x8* __restrict__ whpk){
  int P = blockIdx.x * 256 + threadIdx.x;      // 524,288 total
  int lane = P & 63;
  int q = P >> 6;
  int nt = q & 1; int ks = (q >> 1) & 1; int kt = (q >> 2) & 15; int wg = q >> 6;
  int col16 = lane & 15;
  int g = nt * 2 + (col16 >> 3);
  int c = wg * 8 + (col16 & 7);
  int k0 = kt * 64 + ks * 32 + (lane >> 4) * 8;
  const float* W = (g == 0) ? Whi : (g == 1) ? Whf : (g == 2) ? Whg : Who;
  s16x8 o;
  #pragma unroll
  for (int j = 0; j < 8; ++j) o[j] = f2bf(W[(size_t)(k0 + j) * HID + c]);
  whpk[P] = o;
}

// ---------------- init: bias sums, h0 packed, barrier reset ----------------
__global__ __launch_bounds__(256) void init_kernel(const float* __restrict__ h0,
    const float* bii, const float* bif, const float* big, const float* bio,
    const float* bhi, const float* bhf, const float* bhg, const float* bho,
    float* __restrict__ bias_sum, s16x8* __restrict__ hA0, int* __restrict__ bar){
  int T = blockIdx.x * 256 + threadIdx.x;
  if (T < 4096){
    int g = T >> 10, c = T & 1023;
    const float* bi = (g == 0) ? bii : (g == 1) ? bif : (g == 2) ? big : bio;
    const float* bh = (g == 0) ? bhi : (g == 1) ? bhf : (g == 2) ? bhg : bho;
    bias_sum[T] = bi[c] + bh[c];
  } else if (T < 8192){
    int u = T - 4096;                 // 4096 units of 8 bf16
    int lane = u & 63; int q = u >> 6;
    int kstep = q & 31; int mtb = q >> 5;
    int b = mtb * 16 + (lane & 15);
    int col0 = kstep * 32 + (lane >> 4) * 8;
    const float* src = h0 + (size_t)b * HID + col0;
    s16x8 o;
    #pragma unroll
    for (int j = 0; j < 8; ++j) o[j] = f2bf(src[j]);
    // store via agent-scope so the coop kernel's sc1 loads see it
    u64 lo = (u64)(unsigned short)o[0] | ((u64)(unsigned short)o[1]<<16)
           | ((u64)(unsigned short)o[2]<<32) | ((u64)(unsigned short)o[3]<<48);
    u64 hi = (u64)(unsigned short)o[4] | ((u64)(unsigned short)o[5]<<16)
           | ((u64)(unsigned short)o[6]<<32) | ((u64)(unsigned short)o[7]<<48);
    __hip_atomic_store((u64*)hA0 + 2*u,     lo, __ATOMIC_RELAXED, __HIP_MEMORY_SCOPE_AGENT);
    __hip_atomic_store((u64*)hA0 + 2*u + 1, hi, __ATOMIC_RELAXED, __HIP_MEMORY_SCOPE_AGENT);
  } else if (T < 8192 + 17){
    bar[T - 8192] = 0;                // 16 leaf counters + 1 root
  }
}

// ---------------- phase 1: XP = x @ [Wii|Wif|Wig|Wio] + (b_i + b_h) ----------------
// Output: XP[t][b][c][gate] bf16 (8B/thread read in recurrence).
__global__ __launch_bounds__(256) void gemm_xp_kernel(const s16x8* __restrict__ xpk,
    const s16x8* __restrict__ wxpk, const float* __restrict__ bias_sum,
    short* __restrict__ XP){
  const int mb = blockIdx.x, nb = blockIdx.y;
  const int tid = threadIdx.x, lane = tid & 63, wave = tid >> 6;
  const int wr = wave >> 1, wc = wave & 1;
  __shared__ s16x8 sA[1024];   // 16KB
  __shared__ s16x8 sB[1024];   // 16KB
  f32x4 acc[4][4] = {};
  const s16x8* gA = xpk + (size_t)(mb * 16) * 1024;
  const s16x8* gB = wxpk + (size_t)(nb * 16) * 1024;
  for (int kt = 0; kt < 16; ++kt){
    __syncthreads();
    #pragma unroll
    for (int i = 0; i < 4; ++i){
      sA[i * 256 + tid] = gA[(size_t)kt * 1024 + i * 256 + tid];
      sB[i * 256 + tid] = gB[(size_t)kt * 1024 + i * 256 + tid];
    }
    __syncthreads();
    #pragma unroll
    for (int ks = 0; ks < 2; ++ks){
      s16x8 af[4], bfr[4];
      #pragma unroll
      for (int i = 0; i < 4; ++i) af[i] = sA[(ks * 8 + wr * 4 + i) * 64 + lane];
      #pragma unroll
      for (int j = 0; j < 4; ++j) bfr[j] = sB[(ks * 8 + wc * 4 + j) * 64 + lane];
      #pragma unroll
      for (int i = 0; i < 4; ++i)
        #pragma unroll
        for (int j = 0; j < 4; ++j)
          acc[i][j] = __builtin_amdgcn_mfma_f32_16x16x32_bf16(af[i], bfr[j], acc[i][j], 0, 0, 0);
    }
  }
  #pragma unroll
  for (int i = 0; i < 4; ++i){
    const int m_base = mb * 128 + (wr * 4 + i) * 16 + ((lane >> 4) << 2);
    #pragma unroll
    for (int j = 0; j < 4; ++j){
      const int n = nb * 128 + (wc * 4 + j) * 16 + (lane & 15);
      const float bias = bias_sum[n];
      const int g = n >> 10, c = n & 1023;
      #pragma unroll
      for (int r = 0; r < 4; ++r){
        const int m = m_base + r;
        const int tt = m & 511, bb = m >> 9;
        XP[(((size_t)(tt * 32 + bb) << 10) + c) * 4 + g] = f2bf(acc[i][j][r] + bias);
      }
    }
  }
}

// ---------------- phase 2: persistent recurrence; fence-free barrier ----------------
// h exchange via RELAXED/AGENT (sc1) u64 atomics -> coherent LLC, no L2 wb/inv.
// Everything else (XP, W_h, out) stays on the normal cached path.
__global__ __launch_bounds__(256, 1) void lstm_rec_kernel(const s16x8* __restrict__ whpk,
    s16x8* __restrict__ hA, s16x8* __restrict__ hB, const short* __restrict__ XP,
    const float* __restrict__ c0, float* __restrict__ out, float* __restrict__ htct,
    int* __restrict__ bar)
{
  extern __shared__ char smem[];
  s16x8* sW  = (s16x8*)smem;                         // 64KB
  float* pre = (float*)(smem + 65536);               // [32][33] padded
  unsigned short* hstage = (unsigned short*)(smem + 65536 + 4224);  // [32][8]

  const int wg = blockIdx.x;
  const int tid = threadIdx.x, lane = tid & 63, wave = tid >> 6;
  const int mt = wave >> 1, nt = wave & 1;

  // stage this WG's W_h slice into LDS once
  {
    const s16x8* gW = whpk + (size_t)wg * 4096;
    #pragma unroll
    for (int i = 0; i < 16; ++i) sW[i * 256 + tid] = gW[i * 256 + tid];
  }

  // per-thread epilogue identity
  const int b = tid >> 3, cc = tid & 7;
  const int hcol = wg * 8 + cc;
  float c = c0[b * HID + hcol];

  const int prow = mt * 16 + ((lane >> 4) << 2);
  const int pcol = nt * 16 + (lane & 15);

  const u64* h_cur = (const u64*)hA;
  u64* h_nxt = (u64*)hB;

  // wave-0 h-store geometry (64 u64 per WG, 2 contiguous 256B chunks)
  const int sb_blk = tid >> 5, sb_k = tid & 31;
  const int sb_unit = (sb_blk * 32 + (wg >> 2)) * 64 + (wg & 3) * 16;
  const size_t sb_q = (size_t)sb_unit * 2 + sb_k;
  const unsigned short* sb_src = hstage + ((sb_blk * 16 + (sb_k >> 1)) * 8 + (sb_k & 1) * 4);

  // prefetch XP for t=0
  s16x4 xp = *(const s16x4*)(XP + ((((size_t)b) << 10) + hcol) * 4);

  __syncthreads();

  for (int t = 0; t < SEQ; ++t){
    // ---- h @ W_h : 4 independent partial chains of 8 MFMAs ----
    f32x4 a0 = {0.f,0.f,0.f,0.f}, a1 = a0, a2 = a0, a3 = a0;
    #pragma unroll
    for (int kk = 0; kk < 8; ++kk){
      U128 h0f, h1f, h2f, h3f;
      {
        int u = (mt * 32 + 0 * 8 + kk) * 64 + lane;
        h0f.q.lo = __hip_atomic_load(h_cur + 2*u,   __ATOMIC_RELAXED, __HIP_MEMORY_SCOPE_AGENT);
        h0f.q.hi = __hip_atomic_load(h_cur + 2*u+1, __ATOMIC_RELAXED, __HIP_MEMORY_SCOPE_AGENT);
      }
      {
        int u = (mt * 32 + 1 * 8 + kk) * 64 + lane;
        h1f.q.lo = __hip_atomic_load(h_cur + 2*u,   __ATOMIC_RELAXED, __HIP_MEMORY_SCOPE_AGENT);
        h1f.q.hi = __hip_atomic_load(h_cur + 2*u+1, __ATOMIC_RELAXED, __HIP_MEMORY_SCOPE_AGENT);
      }
      {
        int u = (mt * 32 + 2 * 8 + kk) * 64 + lane;
        h2f.q.lo = __hip_atomic_load(h_cur + 2*u,   __ATOMIC_RELAXED, __HIP_MEMORY_SCOPE_AGENT);
        h2f.q.hi = __hip_atomic_load(h_cur + 2*u+1, __ATOMIC_RELAXED, __HIP_MEMORY_SCOPE_AGENT);
      }
      {
        int u = (mt * 32 + 3 * 8 + kk) * 64 + lane;
        h3f.q.lo = __hip_atomic_load(h_cur + 2*u,   __ATOMIC_RELAXED, __HIP_MEMORY_SCOPE_AGENT);
        h3f.q.hi = __hip_atomic_load(h_cur + 2*u+1, __ATOMIC_RELAXED, __HIP_MEMORY_SCOPE_AGENT);
      }
      a0 = __builtin_amdgcn_mfma_f32_16x16x32_bf16(h0f.v, sW[((0*8+kk)*2+nt)*64+lane], a0, 0, 0, 0);
      a1 = __builtin_amdgcn_mfma_f32_16x16x32_bf16(h1f.v, sW[((1*8+kk)*2+nt)*64+lane], a1, 0, 0, 0);
      a2 = __builtin_amdgcn_mfma_f32_16x16x32_bf16(h2f.v, sW[((2*8+kk)*2+nt)*64+lane], a2, 0, 0, 0);
      a3 = __builtin_amdgcn_mfma_f32_16x16x32_bf16(h3f.v, sW[((3*8+kk)*2+nt)*64+lane], a3, 0, 0, 0);
    }
    f32x4 acc = (a0 + a1) + (a2 + a3);

    pre[(prow + 0) * 33 + pcol] = acc[0];
    pre[(prow + 1) * 33 + pcol] = acc[1];
    pre[(prow + 2) * 33 + pcol] = acc[2];
    pre[(prow + 3) * 33 + pcol] = acc[3];
    __syncthreads();

    float p0 = pre[b * 33 + 0 * 8 + cc] + bf2f(xp[0]);
    float p1 = pre[b * 33 + 1 * 8 + cc] + bf2f(xp[1]);
    float p2 = pre[b * 33 + 2 * 8 + cc] + bf2f(xp[2]);
    float p3 = pre[b * 33 + 3 * 8 + cc] + bf2f(xp[3]);
    float ig = 1.f / (1.f + __expf(-p0));
    float fg = 1.f / (1.f + __expf(-p1));
    float gg = tanhf(p2);
    float og = 1.f / (1.f + __expf(-p3));
    c = fg * c + ig * gg;
    float h = og * tanhf(c);
    out[((size_t)b * SEQ + t) * HID + hcol] = h;
    if (t == SEQ - 1){
      htct[b * HID + hcol] = h;
      htct[32 * HID + b * HID + hcol] = c;
      break;                      // no barrier after final step
    }
    hstage[b * 8 + cc] = (unsigned short)f2bf(h);

    // prefetch XP for t+1 (latency hides under the barrier)
    const int tn = t + 1;
    s16x4 xp_n = *(const s16x4*)(XP + ((((size_t)tn * 32 + b) << 10) + hcol) * 4);

    __syncthreads();              // hstage ready; pre reads done

    // wave 0: publish h to LLC (sc1), drain, then arrive
    if (tid < 64){
      u64 val = (u64)sb_src[0] | ((u64)sb_src[1] << 16)
              | ((u64)sb_src[2] << 32) | ((u64)sb_src[3] << 48);
      __hip_atomic_store(h_nxt + sb_q, val, __ATOMIC_RELAXED, __HIP_MEMORY_SCOPE_AGENT);
    }
    asm volatile("" ::: "memory");
    if (tid == 0){
      asm volatile("s_waitcnt vmcnt(0)" ::: "memory");
      int old = __hip_atomic_fetch_add(&bar[wg & 15], 1, __ATOMIC_RELAXED,
                                       __HIP_MEMORY_SCOPE_AGENT);
      if (old == 8 * (t + 1) - 1)
        __hip_atomic_fetch_add(&bar[16], 1, __ATOMIC_RELAXED,
                               __HIP_MEMORY_SCOPE_AGENT);
      while (__hip_atomic_load(&bar[16], __ATOMIC_RELAXED,
                               __HIP_MEMORY_SCOPE_AGENT) < 16 * (t + 1))
        __builtin_amdgcn_s_sleep(2);
    }
    __syncthreads();
    asm volatile("" ::: "memory");

    xp = xp_n;
    const u64* tmp = h_cur; h_cur = h_nxt; h_nxt = (u64*)tmp;
  }
}

extern "C" void kernel_launch(void* const* d_in, const int* in_sizes, int n_in,
                              void* d_out, int out_size, void* d_ws, size_t ws_size,
                              hipStream_t stream){
  const float* x   = (const float*)d_in[0];
  const float* h0  = (const float*)d_in[1];
  const float* c0  = (const float*)d_in[2];
  const float* Wii = (const float*)d_in[3];
  const float* Wif = (const float*)d_in[4];
  const float* Wig = (const float*)d_in[5];
  const float* Wio = (const float*)d_in[6];
  const float* Whi = (const float*)d_in[7];
  const float* Whf = (const float*)d_in[8];
  const float* Whg = (const float*)d_in[9];
  const float* Who = (const float*)d_in[10];
  const float* bii = (const float*)d_in[11];
  const float* bif = (const float*)d_in[12];
  const float* big = (const float*)d_in[13];
  const float* bio = (const float*)d_in[14];
  const float* bhi = (const float*)d_in[15];
  const float* bhf = (const float*)d_in[16];
  const float* bhg = (const float*)d_in[17];
  const float* bho = (const float*)d_in[18];

  char* ws = (char*)d_ws;
  s16x8* xpk      = (s16x8*)(ws);                         // 32 MB
  s16x8* wxpk     = (s16x8*)(ws + 33554432ull);           //  8 MB
  s16x8* whpk     = (s16x8*)(ws + 41943040ull);           //  8 MB
  short* XP       = (short*)(ws + 50331648ull);           // 128 MB
  s16x8* hA0      = (s16x8*)(ws + 184549376ull);          // 64 KB
  s16x8* hA1      = (s16x8*)(ws + 184614912ull);          // 64 KB
  float* bias_sum = (float*)(ws + 184811520ull);          // 16 KB
  int*   bar      = (int*)  (ws + 184827904ull);          // 17 ints

  float* out  = (float*)d_out;
  float* htct = out + (size_t)BATCH * SEQ * HID;

  pack_x_kernel<<<8192, 256, 0, stream>>>(x, xpk);
  pack_wx_kernel<<<2048, 256, 0, stream>>>(Wii, Wif, Wig, Wio, wxpk);
  pack_wh_kernel<<<2048, 256, 0, stream>>>(Whi, Whf, Whg, Who, whpk);
  init_kernel<<<33, 256, 0, stream>>>(h0, bii, bif, big, bio,
                                      bhi, bhf, bhg, bho, bias_sum, hA0, bar);
  gemm_xp_kernel<<<dim3(128, 32), 256, 0, stream>>>(xpk, wxpk, bias_sum, XP);

  void* args[] = {(void*)&whpk, (void*)&hA0, (void*)&hA1, (void*)&XP,
                  (void*)&c0, (void*)&out, (void*)&htct, (void*)&bar};
  hipLaunchCooperativeKernel((const void*)lstm_rec_kernel, dim3(NWG), dim3(256),
                             args, 65536 + 4224 + 512, stream);
}

// Round 5
// 3555.974 us; speedup vs baseline: 2.6139x; 1.1325x over previous
//
#include <hip/hip_runtime.h>
#include <cstdint>
#include <cstddef>

typedef __attribute__((ext_vector_type(8))) short s16x8;
typedef __attribute__((ext_vector_type(4))) short s16x4;
typedef __attribute__((ext_vector_type(4))) float f32x4;
typedef unsigned long long u64;

#define HID 1024
#define BATCH 32
#define SEQ 512
#define NWG 128

__device__ __forceinline__ short f2bf(float f){
  unsigned u = __builtin_bit_cast(unsigned, f);
  u = (u + 0x7fffu + ((u >> 16) & 1u)) >> 16;
  return (short)u;
}
__device__ __forceinline__ float bf2f(short s){
  unsigned u = ((unsigned)(unsigned short)s) << 16;
  return __builtin_bit_cast(float, u);
}

union U128 { struct { u64 lo, hi; } q; s16x8 v; };

// ---------------- pack x into A-fragment tiles ----------------
__global__ __launch_bounds__(256) void pack_x_kernel(const float* __restrict__ x,
                                                     s16x8* __restrict__ xpk){
  int P = blockIdx.x * 256 + threadIdx.x;      // 2,097,152 total
  int lane = P & 63;
  int w = (P >> 6) & 15; int ks = w >> 3, mt = w & 7;
  int tile = P >> 10; int kt = tile & 15; int mb = tile >> 4;
  int row = mb * 128 + mt * 16 + (lane & 15);
  int k0 = kt * 64 + ks * 32 + (lane >> 4) * 8;
  const f32x4* src = (const f32x4*)(x + (size_t)row * HID + k0);
  f32x4 v0 = src[0], v1 = src[1];
  s16x8 o;
  o[0]=f2bf(v0[0]); o[1]=f2bf(v0[1]); o[2]=f2bf(v0[2]); o[3]=f2bf(v0[3]);
  o[4]=f2bf(v1[0]); o[5]=f2bf(v1[1]); o[6]=f2bf(v1[2]); o[7]=f2bf(v1[3]);
  xpk[P] = o;
}

// ---------------- pack input weights (4 gates side by side, N=4096) ----------------
__global__ __launch_bounds__(256) void pack_wx_kernel(const float* __restrict__ Wii,
    const float* __restrict__ Wif, const float* __restrict__ Wig,
    const float* __restrict__ Wio, s16x8* __restrict__ wxpk){
  int P = blockIdx.x * 256 + threadIdx.x;      // 524,288 total
  int lane = P & 63;
  int w = (P >> 6) & 15; int ks = w >> 3, nt = w & 7;
  int tile = P >> 10; int kt = tile & 15; int nb = tile >> 4;
  int n = nb * 128 + nt * 16 + (lane & 15);
  int g = n >> 10, c = n & 1023;
  int k0 = kt * 64 + ks * 32 + (lane >> 4) * 8;
  const float* W = (g == 0) ? Wii : (g == 1) ? Wif : (g == 2) ? Wig : Wio;
  s16x8 o;
  #pragma unroll
  for (int j = 0; j < 8; ++j) o[j] = f2bf(W[(size_t)(k0 + j) * HID + c]);
  wxpk[P] = o;
}

// ---------------- pack recurrent weights per rec-kernel workgroup ----------------
// whpk: [wg(128)][kt(16)][ks(2)][nt(2)][lane][8]; col16=lane&15,
// gate = nt*2 + (col16>>3), c = wg*8 + (col16&7), k = kt*64+ks*32+(lane>>4)*8+j
__global__ __launch_bounds__(256) void pack_wh_kernel(const float* __restrict__ Whi,
    const float* __restrict__ Whf, const float* __restrict__ Whg,
    const float* __restrict__ Who, s16x8* __restrict__ whpk){
  int P = blockIdx.x * 256 + threadIdx.x;      // 524,288 total
  int lane = P & 63;
  int q = P >> 6;
  int nt = q & 1; int ks = (q >> 1) & 1; int kt = (q >> 2) & 15; int wg = q >> 6;
  int col16 = lane & 15;
  int g = nt * 2 + (col16 >> 3);
  int c = wg * 8 + (col16 & 7);
  int k0 = kt * 64 + ks * 32 + (lane >> 4) * 8;
  const float* W = (g == 0) ? Whi : (g == 1) ? Whf : (g == 2) ? Whg : Who;
  s16x8 o;
  #pragma unroll
  for (int j = 0; j < 8; ++j) o[j] = f2bf(W[(size_t)(k0 + j) * HID + c]);
  whpk[P] = o;
}

// ---------------- init: bias sums, h0 -> hseq[0], flags reset ----------------
__global__ __launch_bounds__(256) void init_kernel(const float* __restrict__ h0,
    const float* bii, const float* bif, const float* big, const float* bio,
    const float* bhi, const float* bhf, const float* bhg, const float* bho,
    float* __restrict__ bias_sum, u64* __restrict__ hseq, int* __restrict__ flags){
  int T = blockIdx.x * 256 + threadIdx.x;
  if (T < 4096){
    int g = T >> 10, c = T & 1023;
    const float* bi = (g == 0) ? bii : (g == 1) ? bif : (g == 2) ? big : bio;
    const float* bh = (g == 0) ? bhi : (g == 1) ? bhf : (g == 2) ? bhg : bho;
    bias_sum[T] = bi[c] + bh[c];
  } else if (T < 8192){
    int u = T - 4096;                 // 4096 units of 8 bf16 -> hseq slot 0
    int lane = u & 63; int q = u >> 6;
    int kstep = q & 31; int mtb = q >> 5;
    int b = mtb * 16 + (lane & 15);
    int col0 = kstep * 32 + (lane >> 4) * 8;
    const float* src = h0 + (size_t)b * HID + col0;
    s16x8 o;
    #pragma unroll
    for (int j = 0; j < 8; ++j) o[j] = f2bf(src[j]);
    u64 lo = (u64)(unsigned short)o[0] | ((u64)(unsigned short)o[1]<<16)
           | ((u64)(unsigned short)o[2]<<32) | ((u64)(unsigned short)o[3]<<48);
    u64 hi = (u64)(unsigned short)o[4] | ((u64)(unsigned short)o[5]<<16)
           | ((u64)(unsigned short)o[6]<<32) | ((u64)(unsigned short)o[7]<<48);
    __hip_atomic_store(hseq + 2*u,     lo, __ATOMIC_RELAXED, __HIP_MEMORY_SCOPE_AGENT);
    __hip_atomic_store(hseq + 2*u + 1, hi, __ATOMIC_RELAXED, __HIP_MEMORY_SCOPE_AGENT);
  } else if (T < 8192 + SEQ * NWG){
    flags[T - 8192] = 0;              // re-zero every launch (replay-safe)
  }
}

// ---------------- phase 1: XP = x @ [Wii|Wif|Wig|Wio] + (b_i + b_h) ----------------
// Output: XP[t][b][c][gate] bf16 (8B/thread read in recurrence).
__global__ __launch_bounds__(256) void gemm_xp_kernel(const s16x8* __restrict__ xpk,
    const s16x8* __restrict__ wxpk, const float* __restrict__ bias_sum,
    short* __restrict__ XP){
  const int mb = blockIdx.x, nb = blockIdx.y;
  const int tid = threadIdx.x, lane = tid & 63, wave = tid >> 6;
  const int wr = wave >> 1, wc = wave & 1;
  __shared__ s16x8 sA[1024];   // 16KB
  __shared__ s16x8 sB[1024];   // 16KB
  f32x4 acc[4][4] = {};
  const s16x8* gA = xpk + (size_t)(mb * 16) * 1024;
  const s16x8* gB = wxpk + (size_t)(nb * 16) * 1024;
  for (int kt = 0; kt < 16; ++kt){
    __syncthreads();
    #pragma unroll
    for (int i = 0; i < 4; ++i){
      sA[i * 256 + tid] = gA[(size_t)kt * 1024 + i * 256 + tid];
      sB[i * 256 + tid] = gB[(size_t)kt * 1024 + i * 256 + tid];
    }
    __syncthreads();
    #pragma unroll
    for (int ks = 0; ks < 2; ++ks){
      s16x8 af[4], bfr[4];
      #pragma unroll
      for (int i = 0; i < 4; ++i) af[i] = sA[(ks * 8 + wr * 4 + i) * 64 + lane];
      #pragma unroll
      for (int j = 0; j < 4; ++j) bfr[j] = sB[(ks * 8 + wc * 4 + j) * 64 + lane];
      #pragma unroll
      for (int i = 0; i < 4; ++i)
        #pragma unroll
        for (int j = 0; j < 4; ++j)
          acc[i][j] = __builtin_amdgcn_mfma_f32_16x16x32_bf16(af[i], bfr[j], acc[i][j], 0, 0, 0);
    }
  }
  #pragma unroll
  for (int i = 0; i < 4; ++i){
    const int m_base = mb * 128 + (wr * 4 + i) * 16 + ((lane >> 4) << 2);
    #pragma unroll
    for (int j = 0; j < 4; ++j){
      const int n = nb * 128 + (wc * 4 + j) * 16 + (lane & 15);
      const float bias = bias_sum[n];
      const int g = n >> 10, c = n & 1023;
      #pragma unroll
      for (int r = 0; r < 4; ++r){
        const int m = m_base + r;
        const int tt = m & 511, bb = m >> 9;
        XP[(((size_t)(tt * 32 + bb) << 10) + c) * 4 + g] = f2bf(acc[i][j][r] + bias);
      }
    }
  }
}

// ---------------- phase 2: persistent recurrence; pure data-flow sync ----------------
// hseq: 4-slot rotating h buffer (64KB/slot) in LLC via sc1. flags[t][wg]=1 when
// WG wg's slice of hseq[t&3] is drained. Consumers poll the 512B flag row with one
// wave-wide u64 load + __all. No atomic RMW, no barrier, no fences.
__global__ __launch_bounds__(256, 1) void lstm_rec_kernel(const s16x8* __restrict__ whpk,
    u64* __restrict__ hseq, int* __restrict__ flags, const short* __restrict__ XP,
    const float* __restrict__ c0, float* __restrict__ out, float* __restrict__ htct)
{
  extern __shared__ char smem[];
  s16x8* sW  = (s16x8*)smem;                           // 64KB
  float* pre = (float*)(smem + 65536);                 // [32][33] padded
  unsigned short* hstage = (unsigned short*)(smem + 65536 + 4224);  // [2][256]

  const int wg = blockIdx.x;
  const int tid = threadIdx.x, lane = tid & 63, wave = tid >> 6;
  const int mt = wave >> 1, nt = wave & 1;

  // stage this WG's W_h slice into LDS once
  {
    const s16x8* gW = whpk + (size_t)wg * 4096;
    #pragma unroll
    for (int i = 0; i < 16; ++i) sW[i * 256 + tid] = gW[i * 256 + tid];
  }

  // per-thread epilogue identity
  const int b = tid >> 3, cc = tid & 7;
  const int hcol = wg * 8 + cc;
  float c = c0[b * HID + hcol];

  const int prow = mt * 16 + ((lane >> 4) << 2);
  const int pcol = nt * 16 + (lane & 15);

  // publish geometry (wave 0): lane -> u64 within hseq slot
  const int pub_off = (tid >> 5) * 4096 + (wg >> 2) * 128 + (wg & 3) * 32 + (tid & 31);

  // prefetch XP for t=0
  s16x4 xp = *(const s16x4*)(XP + ((((size_t)b) << 10) + hcol) * 4);

  __syncthreads();

  for (int t = 0; t < SEQ; ++t){
    // ---- wait for hseq[t&3] to be fully published (skip t=0: init wrote it) ----
    if (t > 0){
      const u64* fp = (const u64*)(flags + (size_t)t * NWG) + lane;
      while (true){
        u64 v = __hip_atomic_load(fp, __ATOMIC_RELAXED, __HIP_MEMORY_SCOPE_AGENT);
        if (__all(v == 0x0000000100000001ull)) break;
        __builtin_amdgcn_s_sleep(1);
      }
    }
    const u64* h_cur = hseq + (size_t)(t & 3) * 8192;

    // ---- h @ W_h : 4 independent partial chains of 8 MFMAs ----
    f32x4 a0 = {0.f,0.f,0.f,0.f}, a1 = a0, a2 = a0, a3 = a0;
    #pragma unroll
    for (int kk = 0; kk < 8; ++kk){
      U128 h0f, h1f, h2f, h3f;
      {
        int u = (mt * 32 + 0 * 8 + kk) * 64 + lane;
        h0f.q.lo = __hip_atomic_load(h_cur + 2*u,   __ATOMIC_RELAXED, __HIP_MEMORY_SCOPE_AGENT);
        h0f.q.hi = __hip_atomic_load(h_cur + 2*u+1, __ATOMIC_RELAXED, __HIP_MEMORY_SCOPE_AGENT);
      }
      {
        int u = (mt * 32 + 1 * 8 + kk) * 64 + lane;
        h1f.q.lo = __hip_atomic_load(h_cur + 2*u,   __ATOMIC_RELAXED, __HIP_MEMORY_SCOPE_AGENT);
        h1f.q.hi = __hip_atomic_load(h_cur + 2*u+1, __ATOMIC_RELAXED, __HIP_MEMORY_SCOPE_AGENT);
      }
      {
        int u = (mt * 32 + 2 * 8 + kk) * 64 + lane;
        h2f.q.lo = __hip_atomic_load(h_cur + 2*u,   __ATOMIC_RELAXED, __HIP_MEMORY_SCOPE_AGENT);
        h2f.q.hi = __hip_atomic_load(h_cur + 2*u+1, __ATOMIC_RELAXED, __HIP_MEMORY_SCOPE_AGENT);
      }
      {
        int u = (mt * 32 + 3 * 8 + kk) * 64 + lane;
        h3f.q.lo = __hip_atomic_load(h_cur + 2*u,   __ATOMIC_RELAXED, __HIP_MEMORY_SCOPE_AGENT);
        h3f.q.hi = __hip_atomic_load(h_cur + 2*u+1, __ATOMIC_RELAXED, __HIP_MEMORY_SCOPE_AGENT);
      }
      a0 = __builtin_amdgcn_mfma_f32_16x16x32_bf16(h0f.v, sW[((0*8+kk)*2+nt)*64+lane], a0, 0, 0, 0);
      a1 = __builtin_amdgcn_mfma_f32_16x16x32_bf16(h1f.v, sW[((1*8+kk)*2+nt)*64+lane], a1, 0, 0, 0);
      a2 = __builtin_amdgcn_mfma_f32_16x16x32_bf16(h2f.v, sW[((2*8+kk)*2+nt)*64+lane], a2, 0, 0, 0);
      a3 = __builtin_amdgcn_mfma_f32_16x16x32_bf16(h3f.v, sW[((3*8+kk)*2+nt)*64+lane], a3, 0, 0, 0);
    }
    f32x4 acc = (a0 + a1) + (a2 + a3);

    pre[(prow + 0) * 33 + pcol] = acc[0];
    pre[(prow + 1) * 33 + pcol] = acc[1];
    pre[(prow + 2) * 33 + pcol] = acc[2];
    pre[(prow + 3) * 33 + pcol] = acc[3];
    __syncthreads();

    float p0 = pre[b * 33 + 0 * 8 + cc] + bf2f(xp[0]);
    float p1 = pre[b * 33 + 1 * 8 + cc] + bf2f(xp[1]);
    float p2 = pre[b * 33 + 2 * 8 + cc] + bf2f(xp[2]);
    float p3 = pre[b * 33 + 3 * 8 + cc] + bf2f(xp[3]);
    float ig = 1.f / (1.f + __expf(-p0));
    float fg = 1.f / (1.f + __expf(-p1));
    float gg = tanhf(p2);
    float og = 1.f / (1.f + __expf(-p3));
    c = fg * c + ig * gg;
    float h = og * tanhf(c);
    out[((size_t)b * SEQ + t) * HID + hcol] = h;
    if (t == SEQ - 1){
      htct[b * HID + hcol] = h;
      htct[32 * HID + b * HID + hcol] = c;
      break;
    }
    hstage[(t & 1) * 256 + b * 8 + cc] = (unsigned short)f2bf(h);

    // prefetch XP for t+1 (latency hides under publish/poll)
    const int tn = t + 1;
    s16x4 xp_n = *(const s16x4*)(XP + ((((size_t)tn * 32 + b) << 10) + hcol) * 4);

    __syncthreads();              // hstage ready; pre consumed by all waves

    // wave 0: publish h slice to LLC, drain, set flag. Others race ahead.
    if (tid < 64){
      u64 val = ((const u64*)(hstage + (t & 1) * 256))[tid];
      __hip_atomic_store(hseq + (size_t)((t + 1) & 3) * 8192 + pub_off, val,
                         __ATOMIC_RELAXED, __HIP_MEMORY_SCOPE_AGENT);
    }
    if (tid == 0){
      asm volatile("s_waitcnt vmcnt(0)" ::: "memory");
      __hip_atomic_store(&flags[(size_t)(t + 1) * NWG + wg], 1,
                         __ATOMIC_RELAXED, __HIP_MEMORY_SCOPE_AGENT);
    }
    xp = xp_n;
  }
}

extern "C" void kernel_launch(void* const* d_in, const int* in_sizes, int n_in,
                              void* d_out, int out_size, void* d_ws, size_t ws_size,
                              hipStream_t stream){
  const float* x   = (const float*)d_in[0];
  const float* h0  = (const float*)d_in[1];
  const float* c0  = (const float*)d_in[2];
  const float* Wii = (const float*)d_in[3];
  const float* Wif = (const float*)d_in[4];
  const float* Wig = (const float*)d_in[5];
  const float* Wio = (const float*)d_in[6];
  const float* Whi = (const float*)d_in[7];
  const float* Whf = (const float*)d_in[8];
  const float* Whg = (const float*)d_in[9];
  const float* Who = (const float*)d_in[10];
  const float* bii = (const float*)d_in[11];
  const float* bif = (const float*)d_in[12];
  const float* big = (const float*)d_in[13];
  const float* bio = (const float*)d_in[14];
  const float* bhi = (const float*)d_in[15];
  const float* bhf = (const float*)d_in[16];
  const float* bhg = (const float*)d_in[17];
  const float* bho = (const float*)d_in[18];

  char* ws = (char*)d_ws;
  s16x8* xpk      = (s16x8*)(ws);                         // 32 MB
  s16x8* wxpk     = (s16x8*)(ws + 33554432ull);           //  8 MB
  s16x8* whpk     = (s16x8*)(ws + 41943040ull);           //  8 MB
  short* XP       = (short*)(ws + 50331648ull);           // 128 MB
  u64*   hseq     = (u64*)  (ws + 184549376ull);          // 4 x 64 KB rotating
  float* bias_sum = (float*)(ws + 184811520ull);          // 16 KB
  int*   flags    = (int*)  (ws + 184827904ull);          // 512*128 ints = 256 KB

  float* out  = (float*)d_out;
  float* htct = out + (size_t)BATCH * SEQ * HID;

  pack_x_kernel<<<8192, 256, 0, stream>>>(x, xpk);
  pack_wx_kernel<<<2048, 256, 0, stream>>>(Wii, Wif, Wig, Wio, wxpk);
  pack_wh_kernel<<<2048, 256, 0, stream>>>(Whi, Whf, Whg, Who, whpk);
  init_kernel<<<288, 256, 0, stream>>>(h0, bii, bif, big, bio,
                                       bhi, bhf, bhg, bho, bias_sum, hseq, flags);
  gemm_xp_kernel<<<dim3(128, 32), 256, 0, stream>>>(xpk, wxpk, bias_sum, XP);

  void* args[] = {(void*)&whpk, (void*)&hseq, (void*)&flags, (void*)&XP,
                  (void*)&c0, (void*)&out, (void*)&htct};
  hipLaunchCooperativeKernel((const void*)lstm_rec_kernel, dim3(NWG), dim3(256),
                             args, 65536 + 4224 + 1024, stream);
}